// Round 1
// baseline (41.950 us; speedup 1.0000x reference)
//
#include <hip/hip_runtime.h>

// Problem constants (from reference)
#define BB 8
#define CC 512
#define NN 4096   // H*W = 64*64
#define HID 24

// ---------------------------------------------------------------------------
// Kernel 1: g[b,c] = mean_hw(rgb) + mean_hw(chm) + 2/N
// The attention branch reduces to the constant 2/N because softmax over the
// spatial axis sums to 1 and GAP averages exactly that axis.
// One block per (b,c) channel; each channel is 4096 contiguous floats in both
// tensors. 256 threads * 4 float4 per tensor, fully coalesced.
// ---------------------------------------------------------------------------
__global__ __launch_bounds__(256) void gap_kernel(
    const float* __restrict__ rgb,
    const float* __restrict__ chm,
    float* __restrict__ g)
{
    const int bc = blockIdx.x;          // 0..4095  (b*C + c)
    const int t  = threadIdx.x;         // 0..255

    const float4* r4 = reinterpret_cast<const float4*>(rgb + (size_t)bc * NN);
    const float4* c4 = reinterpret_cast<const float4*>(chm + (size_t)bc * NN);

    float s = 0.0f;
    #pragma unroll
    for (int i = 0; i < 4; ++i) {       // 4 * 256 * 4 floats = 4096 per tensor
        float4 a = r4[t + i * 256];
        float4 b = c4[t + i * 256];
        s += (a.x + a.y) + (a.z + a.w) + (b.x + b.y) + (b.z + b.w);
    }

    // wave-64 butterfly reduce
    #pragma unroll
    for (int off = 32; off > 0; off >>= 1)
        s += __shfl_down(s, off, 64);

    __shared__ float ws[4];
    if ((t & 63) == 0) ws[t >> 6] = s;
    __syncthreads();
    if (t == 0) {
        float tot = ws[0] + ws[1] + ws[2] + ws[3];
        g[bc] = tot * (1.0f / NN) + 2.0f / NN;
    }
}

// ---------------------------------------------------------------------------
// Kernel 2: tiny MLP.  h1 = relu(g @ w1^T)  [8,24];  out = sigmoid(h1 @ w2^T) [8]
// Single block; g (16 KB) staged in LDS; 192 threads each own one (b,j) dot.
// ---------------------------------------------------------------------------
__global__ __launch_bounds__(256) void mlp_kernel(
    const float* __restrict__ g,
    const float* __restrict__ w1,   // [24, 512] row-major
    const float* __restrict__ w2,   // [24]
    float* __restrict__ out)        // [8]
{
    __shared__ float gs[BB * CC];   // 16 KB
    __shared__ float h1[BB][HID];

    const int t = threadIdx.x;
    for (int i = t; i < BB * CC; i += 256) gs[i] = g[i];
    __syncthreads();

    if (t < BB * HID) {
        const int b = t / HID, j = t % HID;
        const float* wrow = w1 + j * CC;
        const float* grow = gs + b * CC;
        float acc = 0.0f;
        #pragma unroll 8
        for (int c = 0; c < CC; ++c) acc = fmaf(grow[c], wrow[c], acc);
        h1[b][j] = acc > 0.0f ? acc : 0.0f;
    }
    __syncthreads();

    if (t < BB) {
        float acc = 0.0f;
        #pragma unroll
        for (int j = 0; j < HID; ++j) acc = fmaf(h1[t][j], w2[j], acc);
        out[t] = 1.0f / (1.0f + expf(-acc));
    }
}

extern "C" void kernel_launch(void* const* d_in, const int* in_sizes, int n_in,
                              void* d_out, int out_size, void* d_ws, size_t ws_size,
                              hipStream_t stream) {
    const float* rgb = (const float*)d_in[0];
    const float* chm = (const float*)d_in[1];
    // d_in[2..5] = qkv weights/biases: provably unused (softmax-mean identity)
    const float* w1  = (const float*)d_in[6];   // [24,512]
    const float* w2  = (const float*)d_in[7];   // [1,24]
    float* out = (float*)d_out;                 // [8]

    float* g = (float*)d_ws;                    // 4096 floats = 16 KB scratch

    gap_kernel<<<BB * CC, 256, 0, stream>>>(rgb, chm, g);
    mlp_kernel<<<1, 256, 0, stream>>>(g, w1, w2, out);
}